// Round 5
// baseline (254.778 us; speedup 1.0000x reference)
//
#include <hip/hip_runtime.h>
#include <hip/hip_bf16.h>

#define NB   64
#define SL   1024
#define EMB  128
#define NSK  1000
#define NS   4     // split of i-tiles per j-tile

// bf16 table layout in ws (elements):
#define AI_OFF 0
#define BI_OFF 256000
#define AS_OFF 512000
#define BS_OFF 640000
#define TB_ELEMS 768000
#define ACC_BYTE_OFF (TB_ELEMS * 2)   // acc: [NS][NB][SL] float = 1 MB

using short8  = __attribute__((ext_vector_type(8))) short;
using floatx4 = __attribute__((ext_vector_type(4))) float;

// log5(x) = log2(x) * INV_LOG2_5
#define INV_LOG2_5 0.43067655807339306f

__device__ inline unsigned cvt2(float x, float y) {
    float2 f; f.x = x; f.y = y;
    __hip_bfloat162 h = __float22bfloat162_rn(f);
    unsigned u; __builtin_memcpy(&u, &h, sizeof(u));
    return u;
}

// ---- one-time fp32 -> bf16 table conversion (8 elems/thread) ----
extern "C" __global__ __launch_bounds__(256)
void cvt_tables(const float* __restrict__ ai, const float* __restrict__ bi,
                const float* __restrict__ as, const float* __restrict__ bs,
                unsigned short* __restrict__ dst)
{
    const int t = blockIdx.x * 256 + threadIdx.x;   // 96000 threads
    const long e = (long)t * 8;
    const float* src;
    if      (e < 256000) src = ai + e;
    else if (e < 512000) src = bi + (e - 256000);
    else if (e < 640000) src = as + (e - 512000);
    else                 src = bs + (e - 640000);
    float4 f0 = *(const float4*)src;
    float4 f1 = *(const float4*)(src + 4);
    uint4 pk;
    pk.x = cvt2(f0.x, f0.y); pk.y = cvt2(f0.z, f0.w);
    pk.z = cvt2(f1.x, f1.y); pk.w = cvt2(f1.z, f1.w);
    *(uint4*)(dst + e) = pk;
}

// exact fp32 path for duplicate-timestamp pairs (dt==0, i<j):
// contribution = alpha_dot * exp(beta' * 14.306765580733931)   [= -log(1e-10)/log(5)]
__device__ float fixup_pair(const float* __restrict__ air,
                            const float* __restrict__ bir,
                            const float* __restrict__ asr,
                            const float* __restrict__ bsr) {
    float da = 0.f, db = 0.f;
    for (int k = 0; k < EMB; ++k) {
        da += air[k] * asr[k];
        db += bir[k] * bsr[k];
    }
    float beta = fminf(fmaxf(db + 1.f, 0.f), 10.f);
    return da * __expf(beta * 14.30676558073393f);
}

extern "C" __global__ __launch_bounds__(256, 4)
void hawkes_main(const int*   __restrict__ inp,          // (B,4,L) int32
                 const unsigned short* __restrict__ tb,  // bf16 tables
                 float*       __restrict__ acc)          // [NS][NB][SL] partials
{
    // XOR-swizzled tile: element (row, chunk c of 8 shorts) at chunk c^(row&15).
    // Stride 128 shorts (256 B): uniform <=2-way bank aliasing on b128 ops.
    __shared__ unsigned short lA[2][64][128];   // 32 KB: [0]=alpha_inter, [1]=beta_inter

    const int bid  = blockIdx.x;
    const int b    = bid & (NB - 1);
    const int r    = bid >> 6;                 // 0..31
    const int jt   = 7 - (r >> 2);             // heavy j-tiles dispatch first
    const int s    = r & 3;
    const int tid  = threadIdx.x;
    const int w    = tid >> 6;                 // wave -> two 16-j strips
    const int l    = tid & 63;
    const int quad = l >> 4;
    const int col  = l & 15;

    const int* __restrict__ binp = inp + b * 4 * SL;

    const int j0 = jt * 128 + w * 16 + col;    // strip 0
    const int j1 = j0 + 64;                    // strip 1
    const int sk0 = binp[j0],          sk1 = binp[j1];
    const int tj0 = binp[3 * SL + j0], tj1 = binp[3 * SL + j1];

    // ---- B fragments for both strips, both matrices (fixed per block) ----
    short8 bfa0[4], bfb0[4], bfa1[4], bfb1[4];
    {
        const unsigned short* p0a = tb + AS_OFF + (long)sk0 * EMB + quad * 8;
        const unsigned short* p0b = tb + BS_OFF + (long)sk0 * EMB + quad * 8;
        const unsigned short* p1a = tb + AS_OFF + (long)sk1 * EMB + quad * 8;
        const unsigned short* p1b = tb + BS_OFF + (long)sk1 * EMB + quad * 8;
#pragma unroll
        for (int ks = 0; ks < 4; ++ks) {
            bfa0[ks] = *(const short8*)(p0a + ks * 32);
            bfb0[ks] = *(const short8*)(p0b + ks * 32);
            bfa1[ks] = *(const short8*)(p1a + ks * 32);
            bfb1[ks] = *(const short8*)(p1b + ks * 32);
        }
    }

    const int srow = tid >> 2;                 // staging row 0..63
    const int sq   = tid & 3;                  // 32-elem quarter
    const int sw   = srow & 15;                // write swizzle
    unsigned short* rowA = &lA[0][srow][0];
    unsigned short* rowB = &lA[1][srow][0];

    float sum0 = 0.f, sum1 = 0.f;
    const int itmax = 2 * jt + 1;

    if (s <= itmax) {
        // ---- prefetch first tile ----
        uint4 pa0, pa1, pa2, pa3, pb0, pb1, pb2, pb3;
        {
            const int irow  = s * 64 + srow;
            const int ski   = binp[irow];
            const int li    = binp[2 * SL + irow];
            const long intr = ski + (long)li * NSK;
            const unsigned short* sA  = tb + AI_OFF + intr * EMB + sq * 32;
            const unsigned short* sBm = tb + BI_OFF + intr * EMB + sq * 32;
            pa0 = *(const uint4*)(sA);      pa1 = *(const uint4*)(sA + 8);
            pa2 = *(const uint4*)(sA + 16); pa3 = *(const uint4*)(sA + 24);
            pb0 = *(const uint4*)(sBm);     pb1 = *(const uint4*)(sBm + 8);
            pb2 = *(const uint4*)(sBm + 16);pb3 = *(const uint4*)(sBm + 24);
        }

        for (int it = s; it <= itmax; it += NS) {
            __syncthreads();   // previous compute done -> safe to overwrite LDS
            *(uint4*)(rowA + (((sq * 4 + 0) ^ sw) * 8)) = pa0;
            *(uint4*)(rowA + (((sq * 4 + 1) ^ sw) * 8)) = pa1;
            *(uint4*)(rowA + (((sq * 4 + 2) ^ sw) * 8)) = pa2;
            *(uint4*)(rowA + (((sq * 4 + 3) ^ sw) * 8)) = pa3;
            *(uint4*)(rowB + (((sq * 4 + 0) ^ sw) * 8)) = pb0;
            *(uint4*)(rowB + (((sq * 4 + 1) ^ sw) * 8)) = pb1;
            *(uint4*)(rowB + (((sq * 4 + 2) ^ sw) * 8)) = pb2;
            *(uint4*)(rowB + (((sq * 4 + 3) ^ sw) * 8)) = pb3;

            // issue next tile's loads; latency hides under compute
            if (it + NS <= itmax) {
                const int irow  = (it + NS) * 64 + srow;
                const int ski   = binp[irow];
                const int li    = binp[2 * SL + irow];
                const long intr = ski + (long)li * NSK;
                const unsigned short* sA  = tb + AI_OFF + intr * EMB + sq * 32;
                const unsigned short* sBm = tb + BI_OFF + intr * EMB + sq * 32;
                pa0 = *(const uint4*)(sA);      pa1 = *(const uint4*)(sA + 8);
                pa2 = *(const uint4*)(sA + 16); pa3 = *(const uint4*)(sA + 24);
                pb0 = *(const uint4*)(sBm);     pb1 = *(const uint4*)(sBm + 8);
                pb2 = *(const uint4*)(sBm + 16);pb3 = *(const uint4*)(sBm + 24);
            }
            __syncthreads();   // publish LDS tile

            const int itb = it * 64;
#pragma unroll
            for (int isub = 0; isub < 4; ++isub) {
                floatx4 aa0 = {0.f,0.f,0.f,0.f}, bb0 = {0.f,0.f,0.f,0.f};
                floatx4 aa1 = {0.f,0.f,0.f,0.f}, bb1 = {0.f,0.f,0.f,0.f};
                const unsigned short* rrow0 = &lA[0][isub * 16 + col][0];
                const unsigned short* rrow1 = &lA[1][isub * 16 + col][0];
#pragma unroll
                for (int ks = 0; ks < 4; ++ks) {
                    const int pc = ((ks * 4 + quad) ^ col) * 8;
                    short8 av = *(const short8*)(rrow0 + pc);
                    short8 bv = *(const short8*)(rrow1 + pc);
                    aa0 = __builtin_amdgcn_mfma_f32_16x16x32_bf16(av, bfa0[ks], aa0, 0, 0, 0);
                    aa1 = __builtin_amdgcn_mfma_f32_16x16x32_bf16(av, bfa1[ks], aa1, 0, 0, 0);
                    bb0 = __builtin_amdgcn_mfma_f32_16x16x32_bf16(bv, bfb0[ks], bb0, 0, 0, 0);
                    bb1 = __builtin_amdgcn_mfma_f32_16x16x32_bf16(bv, bfb1[ks], bb1, 0, 0, 0);
                }
                const int ibase = itb + isub * 16 + quad * 4;   // C row = quad*4+reg
                const int4 t4 = *(const int4*)(binp + 3 * SL + ibase);
#pragma unroll
                for (int rr = 0; rr < 4; ++rr) {
                    const int ti = (rr == 0) ? t4.x : (rr == 1) ? t4.y : (rr == 2) ? t4.z : t4.w;
                    // sorted times => (i<j && dt>0) <=> dt>0 ; dt==0 dups handled in finalize
                    {
                        const int dt = tj0 - ti;
                        float lc  = __log2f((float)dt);
                        float nb  = fminf(fmaxf(bb0[rr] + 1.f, 0.f), 10.f) * (-INV_LOG2_5);
                        float arg = (dt > 0) ? nb * lc : -__builtin_inff();
                        sum0 += aa0[rr] * exp2f(arg);
                    }
                    {
                        const int dt = tj1 - ti;
                        float lc  = __log2f((float)dt);
                        float nb  = fminf(fmaxf(bb1[rr] + 1.f, 0.f), 10.f) * (-INV_LOG2_5);
                        float arg = (dt > 0) ? nb * lc : -__builtin_inff();
                        sum1 += aa1[rr] * exp2f(arg);
                    }
                }
            }
        }
    }

    // reduce the 4 quads holding the same j
    sum0 += __shfl_xor(sum0, 16, 64); sum0 += __shfl_xor(sum0, 32, 64);
    sum1 += __shfl_xor(sum1, 16, 64); sum1 += __shfl_xor(sum1, 32, 64);

    if (quad == 0) {
        float* as_ = acc + (((long)s * NB + b) << 10);
        as_[j0] = sum0;       // write-once per (s,b,j): no init, no atomics
        as_[j1] = sum1;
    }
}

extern "C" __global__ __launch_bounds__(256)
void hawkes_finalize(const int* __restrict__ inp, const float* __restrict__ pbase,
                     const float* __restrict__ sbase,
                     const float* __restrict__ ai, const float* __restrict__ as,
                     const float* __restrict__ bi, const float* __restrict__ bs,
                     const float* __restrict__ acc, float* __restrict__ out)
{
    const int t = blockIdx.x * 256 + threadIdx.x;   // 65536
    const int b = t >> 10, j = t & (SL - 1);
    const int* binp = inp + b * 4 * SL;
    const int tj   = binp[3 * SL + j];
    const int sk_j = binp[j];

    // exact fp32 correction for duplicate-timestamp pairs (adjacent in sorted order)
    float corr = 0.f;
    for (int i = j - 1; i >= 0 && binp[3 * SL + i] == tj; --i) {
        const int ski = binp[i], li = binp[2 * SL + i];
        const long intr = ski + (long)li * NSK;
        corr += fixup_pair(ai + intr * EMB, bi + intr * EMB,
                           as + (long)sk_j * EMB, bs + (long)sk_j * EMB);
    }

    float sum = acc[t] + acc[NB * SL + t] + acc[2 * NB * SL + t] + acc[3 * NB * SL + t] + corr;
    const float x = pbase[binp[SL + j]] + sbase[sk_j] + sum;
    out[t] = 1.f / (1.f + __expf(-x));
}

extern "C" void kernel_launch(void* const* d_in, const int* in_sizes, int n_in,
                              void* d_out, int out_size, void* d_ws, size_t ws_size,
                              hipStream_t stream) {
    const int*   inp = (const int*)d_in[0];
    const float* pb  = (const float*)d_in[1];
    const float* sb  = (const float*)d_in[2];
    const float* ai  = (const float*)d_in[3];
    const float* as  = (const float*)d_in[4];
    const float* bi  = (const float*)d_in[5];
    const float* bs  = (const float*)d_in[6];

    unsigned short* tb  = (unsigned short*)d_ws;
    float*          acc = (float*)((char*)d_ws + ACC_BYTE_OFF);

    cvt_tables<<<dim3(96000 / 256), dim3(256), 0, stream>>>(ai, bi, as, bs, tb);
    hawkes_main<<<dim3(NB * 8 * NS), dim3(256), 0, stream>>>(inp, tb, acc);
    hawkes_finalize<<<dim3(NB * SL / 256), dim3(256), 0, stream>>>(
        inp, pb, sb, ai, as, bi, bs, acc, (float*)d_out);
}

// Round 6
// 118.422 us; speedup vs baseline: 2.1514x; 2.1514x over previous
//
#include <hip/hip_runtime.h>
#include <hip/hip_bf16.h>

#define NB   64
#define SL   1024
#define EMB  128
#define NSK  1000
#define NS   4     // split of i-tiles per j-tile

// bf16 table layout in ws (elements):
#define AI_OFF 0
#define BI_OFF 256000
#define AS_OFF 512000
#define BS_OFF 640000
#define TB_ELEMS 768000
#define ACC_BYTE_OFF (TB_ELEMS * 2)   // acc: [NS][NB][SL] float = 1 MB

using short8  = __attribute__((ext_vector_type(8))) short;
using floatx4 = __attribute__((ext_vector_type(4))) float;

// log5(x) = log2(x) * INV_LOG2_5
#define INV_LOG2_5 0.43067655807339306f

__device__ inline unsigned cvt2(float x, float y) {
    float2 f; f.x = x; f.y = y;
    __hip_bfloat162 h = __float22bfloat162_rn(f);
    unsigned u; __builtin_memcpy(&u, &h, sizeof(u));
    return u;
}

// ---- one-time fp32 -> bf16 table conversion (8 elems/thread) ----
extern "C" __global__ __launch_bounds__(256)
void cvt_tables(const float* __restrict__ ai, const float* __restrict__ bi,
                const float* __restrict__ as, const float* __restrict__ bs,
                unsigned short* __restrict__ dst)
{
    const int t = blockIdx.x * 256 + threadIdx.x;   // 96000 threads
    const long e = (long)t * 8;
    const float* src;
    if      (e < 256000) src = ai + e;
    else if (e < 512000) src = bi + (e - 256000);
    else if (e < 640000) src = as + (e - 512000);
    else                 src = bs + (e - 640000);
    float4 f0 = *(const float4*)src;
    float4 f1 = *(const float4*)(src + 4);
    uint4 pk;
    pk.x = cvt2(f0.x, f0.y); pk.y = cvt2(f0.z, f0.w);
    pk.z = cvt2(f1.x, f1.y); pk.w = cvt2(f1.z, f1.w);
    *(uint4*)(dst + e) = pk;
}

// exact fp32 path for duplicate-timestamp pairs (dt==0, i<j):
// contribution = alpha_dot * exp(beta' * 14.306765580733931)   [= -log(1e-10)/log(5)]
__device__ float fixup_pair(const float* __restrict__ air,
                            const float* __restrict__ bir,
                            const float* __restrict__ asr,
                            const float* __restrict__ bsr) {
    float da = 0.f, db = 0.f;
    for (int k = 0; k < EMB; ++k) {
        da += air[k] * asr[k];
        db += bir[k] * bsr[k];
    }
    float beta = fminf(fmaxf(db + 1.f, 0.f), 10.f);
    return da * __expf(beta * 14.30676558073393f);
}

// launch_bounds(256,2): VGPR cap 256. (256,4) in R5 capped at 128 and spilled the
// 64-VGPR B-fragment set to scratch (FETCH/WRITE 374/376 MB) -> 191 us. ~150 VGPRs
// here -> 3 waves/SIMD, no spill.
extern "C" __global__ __launch_bounds__(256, 2)
void hawkes_main(const int*   __restrict__ inp,          // (B,4,L) int32
                 const unsigned short* __restrict__ tb,  // bf16 tables
                 float*       __restrict__ acc)          // [NS][NB][SL] partials
{
    // XOR-swizzled tile: element (row, chunk c of 8 shorts) at chunk c^(row&15).
    // Stride 128 shorts (256 B): uniform <=2-way bank aliasing on b128 ops.
    __shared__ unsigned short lA[2][64][128];   // 32 KB: [0]=alpha_inter, [1]=beta_inter

    const int bid  = blockIdx.x;
    const int b    = bid & (NB - 1);
    const int r    = bid >> 6;                 // 0..31
    const int jt   = 7 - (r >> 2);             // heavy j-tiles dispatch first
    const int s    = r & 3;
    const int tid  = threadIdx.x;
    const int w    = tid >> 6;                 // wave -> two 16-j strips
    const int l    = tid & 63;
    const int quad = l >> 4;
    const int col  = l & 15;

    const int* __restrict__ binp = inp + b * 4 * SL;

    const int j0 = jt * 128 + w * 16 + col;    // strip 0
    const int j1 = j0 + 64;                    // strip 1
    const int sk0 = binp[j0],          sk1 = binp[j1];
    const int tj0 = binp[3 * SL + j0], tj1 = binp[3 * SL + j1];

    // ---- B fragments for both strips, both matrices (fixed per block) ----
    short8 bfa0[4], bfb0[4], bfa1[4], bfb1[4];
    {
        const unsigned short* p0a = tb + AS_OFF + (long)sk0 * EMB + quad * 8;
        const unsigned short* p0b = tb + BS_OFF + (long)sk0 * EMB + quad * 8;
        const unsigned short* p1a = tb + AS_OFF + (long)sk1 * EMB + quad * 8;
        const unsigned short* p1b = tb + BS_OFF + (long)sk1 * EMB + quad * 8;
#pragma unroll
        for (int ks = 0; ks < 4; ++ks) {
            bfa0[ks] = *(const short8*)(p0a + ks * 32);
            bfb0[ks] = *(const short8*)(p0b + ks * 32);
            bfa1[ks] = *(const short8*)(p1a + ks * 32);
            bfb1[ks] = *(const short8*)(p1b + ks * 32);
        }
    }

    const int srow = tid >> 2;                 // staging row 0..63
    const int sq   = tid & 3;                  // 32-elem quarter
    const int sw   = srow & 15;                // write swizzle
    unsigned short* rowA = &lA[0][srow][0];
    unsigned short* rowB = &lA[1][srow][0];

    float sum0 = 0.f, sum1 = 0.f;
    const int itmax = 2 * jt + 1;

    if (s <= itmax) {
        // ---- prefetch first tile ----
        uint4 pa0, pa1, pa2, pa3, pb0, pb1, pb2, pb3;
        {
            const int irow  = s * 64 + srow;
            const int ski   = binp[irow];
            const int li    = binp[2 * SL + irow];
            const long intr = ski + (long)li * NSK;
            const unsigned short* sA  = tb + AI_OFF + intr * EMB + sq * 32;
            const unsigned short* sBm = tb + BI_OFF + intr * EMB + sq * 32;
            pa0 = *(const uint4*)(sA);      pa1 = *(const uint4*)(sA + 8);
            pa2 = *(const uint4*)(sA + 16); pa3 = *(const uint4*)(sA + 24);
            pb0 = *(const uint4*)(sBm);     pb1 = *(const uint4*)(sBm + 8);
            pb2 = *(const uint4*)(sBm + 16);pb3 = *(const uint4*)(sBm + 24);
        }

        for (int it = s; it <= itmax; it += NS) {
            __syncthreads();   // previous compute done -> safe to overwrite LDS
            *(uint4*)(rowA + (((sq * 4 + 0) ^ sw) * 8)) = pa0;
            *(uint4*)(rowA + (((sq * 4 + 1) ^ sw) * 8)) = pa1;
            *(uint4*)(rowA + (((sq * 4 + 2) ^ sw) * 8)) = pa2;
            *(uint4*)(rowA + (((sq * 4 + 3) ^ sw) * 8)) = pa3;
            *(uint4*)(rowB + (((sq * 4 + 0) ^ sw) * 8)) = pb0;
            *(uint4*)(rowB + (((sq * 4 + 1) ^ sw) * 8)) = pb1;
            *(uint4*)(rowB + (((sq * 4 + 2) ^ sw) * 8)) = pb2;
            *(uint4*)(rowB + (((sq * 4 + 3) ^ sw) * 8)) = pb3;

            // issue next tile's loads; latency hides under compute
            if (it + NS <= itmax) {
                const int irow  = (it + NS) * 64 + srow;
                const int ski   = binp[irow];
                const int li    = binp[2 * SL + irow];
                const long intr = ski + (long)li * NSK;
                const unsigned short* sA  = tb + AI_OFF + intr * EMB + sq * 32;
                const unsigned short* sBm = tb + BI_OFF + intr * EMB + sq * 32;
                pa0 = *(const uint4*)(sA);      pa1 = *(const uint4*)(sA + 8);
                pa2 = *(const uint4*)(sA + 16); pa3 = *(const uint4*)(sA + 24);
                pb0 = *(const uint4*)(sBm);     pb1 = *(const uint4*)(sBm + 8);
                pb2 = *(const uint4*)(sBm + 16);pb3 = *(const uint4*)(sBm + 24);
            }
            __syncthreads();   // publish LDS tile

            const int itb = it * 64;
#pragma unroll
            for (int isub = 0; isub < 4; ++isub) {
                floatx4 aa0 = {0.f,0.f,0.f,0.f}, bb0 = {0.f,0.f,0.f,0.f};
                floatx4 aa1 = {0.f,0.f,0.f,0.f}, bb1 = {0.f,0.f,0.f,0.f};
                const unsigned short* rrow0 = &lA[0][isub * 16 + col][0];
                const unsigned short* rrow1 = &lA[1][isub * 16 + col][0];
#pragma unroll
                for (int ks = 0; ks < 4; ++ks) {
                    const int pc = ((ks * 4 + quad) ^ col) * 8;
                    short8 av = *(const short8*)(rrow0 + pc);
                    short8 bv = *(const short8*)(rrow1 + pc);
                    aa0 = __builtin_amdgcn_mfma_f32_16x16x32_bf16(av, bfa0[ks], aa0, 0, 0, 0);
                    aa1 = __builtin_amdgcn_mfma_f32_16x16x32_bf16(av, bfa1[ks], aa1, 0, 0, 0);
                    bb0 = __builtin_amdgcn_mfma_f32_16x16x32_bf16(bv, bfb0[ks], bb0, 0, 0, 0);
                    bb1 = __builtin_amdgcn_mfma_f32_16x16x32_bf16(bv, bfb1[ks], bb1, 0, 0, 0);
                }
                const int ibase = itb + isub * 16 + quad * 4;   // C row = quad*4+reg
                const int4 t4 = *(const int4*)(binp + 3 * SL + ibase);
#pragma unroll
                for (int rr = 0; rr < 4; ++rr) {
                    const int ti = (rr == 0) ? t4.x : (rr == 1) ? t4.y : (rr == 2) ? t4.z : t4.w;
                    // sorted times => (i<j && dt>0) <=> dt>0 ; dt==0 dups handled in finalize
                    {
                        const int dt = tj0 - ti;
                        float lc  = __log2f((float)dt);
                        float nb  = fminf(fmaxf(bb0[rr] + 1.f, 0.f), 10.f) * (-INV_LOG2_5);
                        float arg = (dt > 0) ? nb * lc : -__builtin_inff();
                        sum0 += aa0[rr] * exp2f(arg);
                    }
                    {
                        const int dt = tj1 - ti;
                        float lc  = __log2f((float)dt);
                        float nb  = fminf(fmaxf(bb1[rr] + 1.f, 0.f), 10.f) * (-INV_LOG2_5);
                        float arg = (dt > 0) ? nb * lc : -__builtin_inff();
                        sum1 += aa1[rr] * exp2f(arg);
                    }
                }
            }
        }
    }

    // reduce the 4 quads holding the same j
    sum0 += __shfl_xor(sum0, 16, 64); sum0 += __shfl_xor(sum0, 32, 64);
    sum1 += __shfl_xor(sum1, 16, 64); sum1 += __shfl_xor(sum1, 32, 64);

    if (quad == 0) {
        float* as_ = acc + (((long)s * NB + b) << 10);
        as_[j0] = sum0;       // write-once per (s,b,j): no init, no atomics
        as_[j1] = sum1;
    }
}

extern "C" __global__ __launch_bounds__(256)
void hawkes_finalize(const int* __restrict__ inp, const float* __restrict__ pbase,
                     const float* __restrict__ sbase,
                     const float* __restrict__ ai, const float* __restrict__ as,
                     const float* __restrict__ bi, const float* __restrict__ bs,
                     const float* __restrict__ acc, float* __restrict__ out)
{
    const int t = blockIdx.x * 256 + threadIdx.x;   // 65536
    const int b = t >> 10, j = t & (SL - 1);
    const int* binp = inp + b * 4 * SL;
    const int tj   = binp[3 * SL + j];
    const int sk_j = binp[j];

    // exact fp32 correction for duplicate-timestamp pairs (adjacent in sorted order)
    float corr = 0.f;
    for (int i = j - 1; i >= 0 && binp[3 * SL + i] == tj; --i) {
        const int ski = binp[i], li = binp[2 * SL + i];
        const long intr = ski + (long)li * NSK;
        corr += fixup_pair(ai + intr * EMB, bi + intr * EMB,
                           as + (long)sk_j * EMB, bs + (long)sk_j * EMB);
    }

    float sum = acc[t] + acc[NB * SL + t] + acc[2 * NB * SL + t] + acc[3 * NB * SL + t] + corr;
    const float x = pbase[binp[SL + j]] + sbase[sk_j] + sum;
    out[t] = 1.f / (1.f + __expf(-x));
}

extern "C" void kernel_launch(void* const* d_in, const int* in_sizes, int n_in,
                              void* d_out, int out_size, void* d_ws, size_t ws_size,
                              hipStream_t stream) {
    const int*   inp = (const int*)d_in[0];
    const float* pb  = (const float*)d_in[1];
    const float* sb  = (const float*)d_in[2];
    const float* ai  = (const float*)d_in[3];
    const float* as  = (const float*)d_in[4];
    const float* bi  = (const float*)d_in[5];
    const float* bs  = (const float*)d_in[6];

    unsigned short* tb  = (unsigned short*)d_ws;
    float*          acc = (float*)((char*)d_ws + ACC_BYTE_OFF);

    cvt_tables<<<dim3(96000 / 256), dim3(256), 0, stream>>>(ai, bi, as, bs, tb);
    hawkes_main<<<dim3(NB * 8 * NS), dim3(256), 0, stream>>>(inp, tb, acc);
    hawkes_finalize<<<dim3(NB * SL / 256), dim3(256), 0, stream>>>(
        inp, pb, sb, ai, as, bi, bs, acc, (float*)d_out);
}